// Round 1
// 415.286 us; speedup vs baseline: 1.0094x; 1.0094x over previous
//
#include <hip/hip_runtime.h>

#define B_  16
#define N_  2048
#define D_  1024
#define P_  1024
#define M_  (B_*N_)   // 32768

typedef __attribute__((ext_vector_type(8))) short bf16x8;
typedef __attribute__((ext_vector_type(4))) float f32x4;

__device__ __forceinline__ float bf2f(unsigned short u) {
    union { unsigned int i; float f; } v; v.i = ((unsigned int)u) << 16; return v.f;
}
__device__ __forceinline__ unsigned short f2bf(float f) {
    union { unsigned int i; float f; } v; v.f = f;
    unsigned int i = v.i;
    return (unsigned short)((i + 0x7FFFu + ((i >> 16) & 1u)) >> 16);   // RNE
}

__device__ __forceinline__ void async_cp16(const void* g, void* s) {
    __builtin_amdgcn_global_load_lds((const __attribute__((address_space(1))) void*)g,
                                     (__attribute__((address_space(3))) void*)s,
                                     16, 0, 0);
}

// one kernel converts all three fp32 inputs to bf16
__global__ void cvt_all_k(const float* __restrict__ x,  unsigned short* __restrict__ xb,
                          const float* __restrict__ Wp, unsigned short* __restrict__ Wpb,
                          const float* __restrict__ Wv, unsigned short* __restrict__ Wvb)
{
    const int stride = gridDim.x * 256 * 4;
    const int base = (blockIdx.x * 256 + threadIdx.x) * 4;
    for (int i = base; i < M_ * D_; i += stride) {
        float4 v = *(const float4*)(x + i);
        union { unsigned short u[4]; unsigned long long ll; } p;
        p.u[0]=f2bf(v.x); p.u[1]=f2bf(v.y); p.u[2]=f2bf(v.z); p.u[3]=f2bf(v.w);
        *(unsigned long long*)(xb + i) = p.ll;
    }
    for (int i = base; i < P_ * D_; i += stride) {
        float4 v = *(const float4*)(Wp + i);
        union { unsigned short u[4]; unsigned long long ll; } p;
        p.u[0]=f2bf(v.x); p.u[1]=f2bf(v.y); p.u[2]=f2bf(v.z); p.u[3]=f2bf(v.w);
        *(unsigned long long*)(Wpb + i) = p.ll;
    }
    for (int i = base; i < P_ * D_; i += stride) {
        float4 v = *(const float4*)(Wv + i);
        union { unsigned short u[4]; unsigned long long ll; } p;
        p.u[0]=f2bf(v.x); p.u[1]=f2bf(v.y); p.u[2]=f2bf(v.z); p.u[3]=f2bf(v.w);
        *(unsigned long long*)(Wvb + i) = p.ll;
    }
}

// ---------------------------------------------------------------------------
// 256x256-tile, 8-wave, 8-phase counted-vmcnt bf16 GEMM (T2+T3+T4+T5).
//   acc[m,p] = sum_k A[m,k]*W[p,k],  K = 1024, BK = 64, 16 K-tiles.
// LDS 128 KiB: A[2][256][64] + B[2][256][64] bf16, XOR-chunk swizzle
//   (16B chunk c of row r stored at phys chunk c ^ (r&7); staging keeps LDS
//   linear per HW rule and pre-swizzles the GLOBAL column; verified 0 bank
//   conflicts in the previous 128^2 kernel with identical addressing).
// Wave (wr=wave>>2, wc=wave&3) owns C rows {wr*64 + mh*128}, cols
//   {wc*32 + nh*128}; a phase computes quadrant (mh,nh): 12 ds_read_b128,
//   2 global_load_lds (one freed 128-row half-region), 16 MFMA.
// vmcnt(4) only at phases 4/8 -> 6 phases of loads (12 insts/wave) stay in
//   flight across barriers; never drained to 0 inside the loop.
// MODE 0: X1 = f2bf(relu(acc+b)) via LDS-staged coalesced 16B stores
//   (fixes the measured 2x HBM write amplification of 2B scatter stores).
// MODE 1: out = att[m]*relu(acc+b), direct fp32 stores (already ideal).
// ---------------------------------------------------------------------------
template<int MODE>
__global__ __launch_bounds__(512, 2) void gemm8p(const unsigned short* __restrict__ A,
                                                 const unsigned short* __restrict__ W,
                                                 const float* __restrict__ bias,
                                                 const float* __restrict__ att,
                                                 void* __restrict__ Cv)
{
    __shared__ unsigned short smem[65536];   // 128 KiB: A0|A1|B0|B1, 16384 shorts each

    // XCD-aware remap: 512 blocks, id&7 = XCD, each XCD gets 16 row-tiles x 4 col-tiles
    const int id  = blockIdx.x;
    const int xcd = id & 7, idx = id >> 3;
    const int bx  = idx & 3;
    const int by  = xcd * 16 + (idx >> 2);
    const int m0  = by << 8, p0 = bx << 8;

    const int t    = threadIdx.x;
    const int lane = t & 63, wave = t >> 6;
    const int wr   = wave >> 2, wc = wave & 3;
    const int lr   = lane & 15, lq = lane >> 4;

    // fragment addressing (identical math to the verified 128^2 kernel)
    const int aBase = (wr * 64 + lr) * 64;
    const int bBase = (wc * 32 + lr) * 64;
    const int c0 = ((lq       ^ (lr & 7)) & 7) * 8;   // k-half 0 chunk (swizzled)
    const int c1 = (((lq | 4) ^ (lr & 7)) & 7) * 8;   // k-half 1 chunk

    // staging: 1 inst = 64 rows x 128B across 512 threads; per wave dst is
    // wave-uniform base + lane*16B (HW rule); global col pre-swizzled.
    const int srowT = t >> 3;                          // 0..63
    const int slot8 = (t & 7) * 8;
    const int lch8  = (((t & 7) ^ (srowT & 7)) & 7) * 8;
    const unsigned short* Ag = A + ((size_t)m0 << 10) + lch8;
    const unsigned short* Bg = W + ((size_t)p0 << 10) + lch8;

    auto stageA = [&](int buf, int rb, int tt) {       // stages A rows [rb, rb+128)
        const unsigned short* s = Ag + ((size_t)(rb + srowT) << 10) + (tt << 6);
        async_cp16(s,                      smem + buf * 16384 + (rb + srowT) * 64 + slot8);
        async_cp16(s + ((size_t)64 << 10), smem + buf * 16384 + (rb + 64 + srowT) * 64 + slot8);
    };
    auto stageB = [&](int buf, int rb, int tt) {       // stages W rows [rb, rb+128)
        const unsigned short* s = Bg + ((size_t)(rb + srowT) << 10) + (tt << 6);
        async_cp16(s,                      smem + 32768 + buf * 16384 + (rb + srowT) * 64 + slot8);
        async_cp16(s + ((size_t)64 << 10), smem + 32768 + buf * 16384 + (rb + 64 + srowT) * 64 + slot8);
    };

    f32x4 acc[8][4];
    #pragma unroll
    for (int i = 0; i < 8; ++i)
        #pragma unroll
        for (int j = 0; j < 4; ++j) acc[i][j] = (f32x4){0.f, 0.f, 0.f, 0.f};

    // prologue: tile0 -> buf0 (8 insts), tile1 -> buf1 (8 insts); wait tile0 only
    stageA(0, 0, 0); stageA(0, 128, 0); stageB(0, 0, 0); stageB(0, 128, 0);
    stageA(1, 0, 1); stageA(1, 128, 1); stageB(1, 0, 1); stageB(1, 128, 1);
    asm volatile("s_waitcnt vmcnt(8)" ::: "memory");
    __builtin_amdgcn_sched_barrier(0);
    __builtin_amdgcn_s_barrier();

#define VMW4 do { asm volatile("s_waitcnt vmcnt(4)" ::: "memory"); \
                  __builtin_amdgcn_sched_barrier(0); } while (0)
#define NOVM ((void)0)
#define PHASE(BUFC, MH, NH, STAGE_STMT, DO_VM) do {                                   \
    bf16x8 afr[4][2], bfr[2][2];                                                      \
    const unsigned short* Ab_ = smem + (BUFC) * 16384 + (MH) * 8192 + aBase;          \
    const unsigned short* Bb_ = smem + 32768 + (BUFC) * 16384 + (NH) * 8192 + bBase;  \
    _Pragma("unroll")                                                                 \
    for (int i_ = 0; i_ < 4; ++i_) {                                                  \
        afr[i_][0] = *(const bf16x8*)(Ab_ + i_ * 1024 + c0);                          \
        afr[i_][1] = *(const bf16x8*)(Ab_ + i_ * 1024 + c1);                          \
    }                                                                                 \
    _Pragma("unroll")                                                                 \
    for (int j_ = 0; j_ < 2; ++j_) {                                                  \
        bfr[j_][0] = *(const bf16x8*)(Bb_ + j_ * 1024 + c0);                          \
        bfr[j_][1] = *(const bf16x8*)(Bb_ + j_ * 1024 + c1);                          \
    }                                                                                 \
    STAGE_STMT;                                                                       \
    __builtin_amdgcn_s_barrier();                                                     \
    asm volatile("s_waitcnt lgkmcnt(0)" ::: "memory");                                \
    __builtin_amdgcn_sched_barrier(0);                                                \
    __builtin_amdgcn_s_setprio(1);                                                    \
    _Pragma("unroll")                                                                 \
    for (int h_ = 0; h_ < 2; ++h_)                                                    \
        _Pragma("unroll")                                                             \
        for (int i_ = 0; i_ < 4; ++i_)                                                \
            _Pragma("unroll")                                                         \
            for (int j_ = 0; j_ < 2; ++j_)                                            \
                acc[(MH) * 4 + i_][(NH) * 2 + j_] =                                   \
                    __builtin_amdgcn_mfma_f32_16x16x32_bf16(                          \
                        afr[i_][h_], bfr[j_][h_],                                     \
                        acc[(MH) * 4 + i_][(NH) * 2 + j_], 0, 0, 0);                  \
    __builtin_amdgcn_s_setprio(0);                                                    \
    DO_VM;                                                                            \
    __builtin_amdgcn_s_barrier();                                                     \
} while (0)

    // 8 iterations x 2 K-tiles; staging fills each half-region one phase after
    // it is freed by the quadrant order (0,0),(1,0),(0,1),(1,1).
    #pragma unroll 1
    for (int it = 0; it < 8; ++it) {
        const int t1 = 2 * it + 1;
        const int t2 = (2 * it + 2) & 15;   // wraps harmlessly on last iter
        const int t3 = (2 * it + 3) & 15;
        PHASE(0, 0, 0, { if (it) stageA(1, 128, t1); }, NOVM);  // buf1.A.mh1 <- t1
        PHASE(0, 1, 0, { if (it) stageB(1, 128, t1); }, NOVM);  // buf1.B.nh1 <- t1
        PHASE(0, 0, 1, stageB(0, 0,   t2), NOVM);               // buf0.B.nh0 <- t2
        PHASE(0, 1, 1, stageA(0, 0,   t2), VMW4);               // buf0.A.mh0 <- t2
        PHASE(1, 0, 0, stageA(0, 128, t2), NOVM);               // buf0.A.mh1 <- t2
        PHASE(1, 1, 0, stageB(0, 128, t2), NOVM);               // buf0.B.nh1 <- t2
        PHASE(1, 0, 1, stageB(1, 0,   t3), NOVM);               // buf1.B.nh0 <- t3
        PHASE(1, 1, 1, stageA(1, 0,   t3), VMW4);               // buf1.A.mh0 <- t3
    }
#undef PHASE
#undef VMW4
#undef NOVM

    // drain stale prefetches before reusing LDS / ending the wave
    asm volatile("s_waitcnt vmcnt(0)" ::: "memory");
    __syncthreads();

    // C/D layout: col = lane&15, row = (lane>>4)*4 + reg   [m89-verified]
    // row = m0 + (mi>>2)*128 + wr*64 + (mi&3)*16 + lq*4 + v
    // col = p0 + (nj>>1)*128 + wc*32 + (nj&1)*16 + lr
    if (MODE == 0) {
        float bi[4];
        #pragma unroll
        for (int nj = 0; nj < 4; ++nj)
            bi[nj] = bias[p0 + ((nj >> 1) << 7) + wc * 32 + ((nj & 1) << 4) + lr];
        unsigned short* Cp = (unsigned short*)Cv;
        #pragma unroll
        for (int mh = 0; mh < 2; ++mh) {          // 128-row half through 64 KiB LDS
            #pragma unroll
            for (int i = 0; i < 4; ++i) {
                const int rl = wr * 64 + i * 16 + lq * 4;
                #pragma unroll
                for (int nj = 0; nj < 4; ++nj) {
                    const int colL = ((nj >> 1) << 7) + wc * 32 + ((nj & 1) << 4) + lr;
                    #pragma unroll
                    for (int v = 0; v < 4; ++v) {
                        const float val = fmaxf(acc[mh * 4 + i][nj][v] + bi[nj], 0.f);
                        smem[(rl + v) * 256 + colL] = f2bf(val);
                    }
                }
            }
            __syncthreads();
            #pragma unroll
            for (int pas = 0; pas < 8; ++pas) {   // coalesced 16B/lane writeback
                const int ix = pas * 512 + t;
                const int row = ix >> 5, ch = ix & 31;
                bf16x8 vv = *(const bf16x8*)(smem + row * 256 + ch * 8);
                *(bf16x8*)(Cp + (size_t)(m0 + mh * 128 + row) * P_ + p0 + ch * 8) = vv;
            }
            __syncthreads();
        }
    } else {
        float* Cp = (float*)Cv;
        #pragma unroll
        for (int mi = 0; mi < 8; ++mi) {
            const int row = m0 + ((mi >> 2) << 7) + wr * 64 + ((mi & 3) << 4) + lq * 4;
            float av[4];
            #pragma unroll
            for (int v = 0; v < 4; ++v) av[v] = att[row + v];
            #pragma unroll
            for (int nj = 0; nj < 4; ++nj) {
                const int col = p0 + ((nj >> 1) << 7) + wc * 32 + ((nj & 1) << 4) + lr;
                const float b0v = bias[col];
                #pragma unroll
                for (int v = 0; v < 4; ++v) {
                    const float val = fmaxf(acc[mi][nj][v] + b0v, 0.f);
                    Cp[(size_t)(row + v) * P_ + col] = val * av[v];
                }
            }
        }
    }
}

// ---------- fallback fp32-staged GEMM (only if ws too small) -----------------
template<int MODE>
__global__ __launch_bounds__(256) void gemm_f32(const float* __restrict__ A,
                                                const float* __restrict__ W,
                                                const float* __restrict__ bias,
                                                const float* __restrict__ att,
                                                void* __restrict__ Cv)
{
    const int K = D_, BK = 32;
    __shared__ float As[128 * 32];
    __shared__ float Bs[128 * 32];
    const int id = blockIdx.x;
    const int bx = (id >> 3) & 7;
    const int by = ((id >> 6) << 3) | (id & 7);
    const int m0 = by * 128, p0 = bx * 128;
    const int wave = threadIdx.x >> 6, lane = threadIdx.x & 63;
    const int wr = wave >> 1, wc = wave & 1;
    const int srow = wave * 32 + (lane >> 3);
    const int scol = (lane & 7) * 4;
    const float* ag = A + (size_t)(m0 + srow) * K + scol;
    const float* bg = W + (size_t)(p0 + srow) * K + scol;
    float* as = &As[srow * BK + scol];
    float* bs = &Bs[srow * BK + scol];
    f32x4 acc[4][4];
    #pragma unroll
    for (int i = 0; i < 4; i++)
        #pragma unroll
        for (int j = 0; j < 4; j++) acc[i][j] = (f32x4){0.f,0.f,0.f,0.f};
    const int lr = lane & 15, lq = lane >> 4;
    const float* Ar = &As[(wr * 64 + lr) * BK + lq * 8];
    const float* Br = &Bs[(wc * 64 + lr) * BK + lq * 8];
    for (int kb = 0; kb < K; kb += BK) {
        #pragma unroll
        for (int s = 0; s < 4; s++) {
            async_cp16(ag + (size_t)s * 8 * K + kb, as + s * 8 * BK);
            async_cp16(bg + (size_t)s * 8 * K + kb, bs + s * 8 * BK);
        }
        __syncthreads();
        bf16x8 af[4], bf[4];
        #pragma unroll
        for (int i = 0; i < 4; i++) {
            f32x4 a0 = *(const f32x4*)(Ar + i * 16 * BK);
            f32x4 a1 = *(const f32x4*)(Ar + i * 16 * BK + 4);
            #pragma unroll
            for (int e = 0; e < 4; e++) {
                union { float f; unsigned int u; } c;
                c.f = a0[e]; af[i][e]     = (short)(c.u >> 16);
                c.f = a1[e]; af[i][e + 4] = (short)(c.u >> 16);
            }
        }
        #pragma unroll
        for (int j = 0; j < 4; j++) {
            f32x4 b0 = *(const f32x4*)(Br + j * 16 * BK);
            f32x4 b1 = *(const f32x4*)(Br + j * 16 * BK + 4);
            #pragma unroll
            for (int e = 0; e < 4; e++) {
                union { float f; unsigned int u; } c;
                c.f = b0[e]; bf[j][e]     = (short)(c.u >> 16);
                c.f = b1[e]; bf[j][e + 4] = (short)(c.u >> 16);
            }
        }
        #pragma unroll
        for (int i = 0; i < 4; i++)
            #pragma unroll
            for (int j = 0; j < 4; j++)
                acc[i][j] = __builtin_amdgcn_mfma_f32_16x16x32_bf16(af[i], bf[j], acc[i][j], 0, 0, 0);
        __syncthreads();
    }
    const int crow0 = m0 + wr * 64 + lq * 4;
    const int ccol0 = p0 + wc * 64 + lr;
    #pragma unroll
    for (int i = 0; i < 4; i++) {
        float attv[4];
        if (MODE == 1) {
            #pragma unroll
            for (int v = 0; v < 4; v++) attv[v] = att[crow0 + i * 16 + v];
        }
        #pragma unroll
        for (int j = 0; j < 4; j++) {
            const int col = ccol0 + j * 16;
            const float bi = bias[col];
            #pragma unroll
            for (int v = 0; v < 4; v++) {
                const int row = crow0 + i * 16 + v;
                float val = fmaxf(acc[i][j][v] + bi, 0.0f);
                if (MODE == 0) ((unsigned short*)Cv)[(size_t)row * P_ + col] = f2bf(val);
                else           ((float*)Cv)[(size_t)row * P_ + col] = val * attv[v];
            }
        }
    }
}

// ---------- fused rownorm + weighted column-reduce + mask-sum ----------------
__global__ __launch_bounds__(256) void fused_nc_k(const unsigned short* __restrict__ X1,
                                                  const float* __restrict__ mask,
                                                  float* __restrict__ inv,
                                                  float* __restrict__ wsv,
                                                  float* __restrict__ msum)
{
    __shared__ float accw[4][1024];
    __shared__ float mred[4];
    const int b = blockIdx.y, nc = blockIdx.x;
    const int wave = threadIdx.x >> 6, lane = threadIdx.x & 63;
    float acc[16];
    #pragma unroll
    for (int e = 0; e < 16; e++) acc[e] = 0.f;
    float msub = 0.f;
    const int rbase = b * N_ + nc * 64 + wave * 16;
    const int nbase = nc * 64 + wave * 16;
    for (int t = 0; t < 16; t++) {
        const int r = rbase + t;
        const unsigned short* row = X1 + (size_t)r * P_;
        bf16x8 u0 = *(const bf16x8*)(row + lane * 16);
        bf16x8 u1 = *(const bf16x8*)(row + lane * 16 + 8);
        float v[16], s = 0.f;
        #pragma unroll
        for (int e = 0; e < 8; e++) { v[e] = bf2f((unsigned short)u0[e]); s += v[e]*v[e]; }
        #pragma unroll
        for (int e = 0; e < 8; e++) { v[8+e] = bf2f((unsigned short)u1[e]); s += v[8+e]*v[8+e]; }
        #pragma unroll
        for (int off = 32; off > 0; off >>= 1) s += __shfl_down(s, off);
        s = __shfl(s, 0);
        const float iv = 1.f / (sqrtf(s) + 1e-8f);
        const float mk = mask[(nbase + t) * B_ + b];
        if (lane == 0) { inv[r] = iv; msub += mk; }
        const float w = mk * iv;
        #pragma unroll
        for (int e = 0; e < 16; e++) acc[e] += w * v[e];
    }
    #pragma unroll
    for (int e = 0; e < 16; e++) accw[wave][e * 64 + lane] = acc[e];   // transposed
    if (lane == 0) mred[wave] = msub;
    __syncthreads();
    #pragma unroll
    for (int q = 0; q < 4; q++) {
        const int p = threadIdx.x * 4 + q;
        const int col = (p & 63) * 16 + (p >> 6);
        float ssum = accw[0][p] + accw[1][p] + accw[2][p] + accw[3][p];
        atomicAdd(&wsv[b * P_ + col], ssum);
    }
    if (threadIdx.x == 0) atomicAdd(&msum[b], mred[0] + mred[1] + mred[2] + mred[3]);
}

// att[r] = inv[r] * <X1[r,:], wsv[b,:]> / msum[b]; one wave per row
__global__ void att_k(const unsigned short* __restrict__ X1,
                      const float* __restrict__ wsvec,
                      const float* __restrict__ inv,
                      const float* __restrict__ msum,
                      float* __restrict__ att)
{
    const int r = blockIdx.x * 4 + (threadIdx.x >> 6);
    const int lane = threadIdx.x & 63;
    const int b = r >> 11;
    const unsigned short* row = X1 + (size_t)r * P_;
    const float* w = wsvec + b * P_;
    bf16x8 u0 = *(const bf16x8*)(row + lane * 8);
    bf16x8 u1 = *(const bf16x8*)(row + 512 + lane * 8);
    float s = 0.f;
    #pragma unroll
    for (int k = 0; k < 8; k++) s += bf2f((unsigned short)u0[k]) * w[lane * 8 + k];
    #pragma unroll
    for (int k = 0; k < 8; k++) s += bf2f((unsigned short)u1[k]) * w[512 + lane * 8 + k];
    #pragma unroll
    for (int off = 32; off > 0; off >>= 1) s += __shfl_down(s, off);
    if (lane == 0) att[r] = s * inv[r] / msum[b];
}

extern "C" void kernel_launch(void* const* d_in, const int* in_sizes, int n_in,
                              void* d_out, int out_size, void* d_ws, size_t ws_size,
                              hipStream_t stream)
{
    const float* x    = (const float*)d_in[0];
    const float* mask = (const float*)d_in[1];
    const float* Wp   = (const float*)d_in[2];
    const float* bp   = (const float*)d_in[3];
    const float* Wv   = (const float*)d_in[4];
    const float* bv   = (const float*)d_in[5];
    float* out = (float*)d_out;

    // X1 (bf16, 64 MiB) parks in d_out's first half; dead before GEMM2 stores.
    unsigned short* X1 = (unsigned short*)d_out;

    const size_t xb_bytes = (size_t)M_ * D_ * 2;
    const size_t wb_bytes = (size_t)P_ * D_ * 2;
    const size_t f_bytes  = 2 * (size_t)M_ * 4 + (size_t)B_ * P_ * 4 + 64;
    const bool big_ws = ws_size >= xb_bytes + 2 * wb_bytes + f_bytes;

    char* ws = (char*)d_ws;
    size_t off = 0;
    unsigned short *xb = nullptr, *Wpb = nullptr, *Wvb = nullptr;
    if (big_ws) {
        xb  = (unsigned short*)(ws + off); off += xb_bytes;
        Wpb = (unsigned short*)(ws + off); off += wb_bytes;
        Wvb = (unsigned short*)(ws + off); off += wb_bytes;
    }
    float* inv  = (float*)(ws + off); off += (size_t)M_ * 4;
    float* att  = (float*)(ws + off); off += (size_t)M_ * 4;
    float* wsv  = (float*)(ws + off); off += (size_t)B_ * P_ * 4;
    float* msum = (float*)(ws + off); off += 64;

    hipMemsetAsync(wsv, 0, (size_t)B_ * P_ * 4 + 64, stream);

    if (big_ws) {
        cvt_all_k<<<2048, 256, 0, stream>>>(x, xb, Wp, Wpb, Wv, Wvb);
        gemm8p<0><<<512, 512, 0, stream>>>(xb, Wpb, bp, nullptr, X1);
    } else {
        const int gblocks = (P_ / 128) * (M_ / 128);
        gemm_f32<0><<<gblocks, 256, 0, stream>>>(x, Wp, bp, nullptr, X1);
    }
    fused_nc_k<<<dim3(32, B_), 256, 0, stream>>>(X1, mask, inv, wsv, msum);
    att_k<<<M_ / 4, 256, 0, stream>>>(X1, wsv, inv, msum, att);
    if (big_ws) gemm8p<1><<<512, 512, 0, stream>>>(xb, Wvb, bv, att, out);
    else {
        const int gblocks = (P_ / 128) * (M_ / 128);
        gemm_f32<1><<<gblocks, 256, 0, stream>>>(x, Wv, bv, att, out);
    }
}

// Round 2
// 410.156 us; speedup vs baseline: 1.0220x; 1.0125x over previous
//
#include <hip/hip_runtime.h>

#define B_  16
#define N_  2048
#define D_  1024
#define P_  1024
#define M_  (B_*N_)   // 32768

typedef __attribute__((ext_vector_type(8))) short bf16x8;
typedef __attribute__((ext_vector_type(4))) float f32x4;

__device__ __forceinline__ float bf2f(unsigned short u) {
    union { unsigned int i; float f; } v; v.i = ((unsigned int)u) << 16; return v.f;
}
__device__ __forceinline__ unsigned short f2bf(float f) {
    union { unsigned int i; float f; } v; v.f = f;
    unsigned int i = v.i;
    return (unsigned short)((i + 0x7FFFu + ((i >> 16) & 1u)) >> 16);   // RNE
}

__device__ __forceinline__ void async_cp16(const void* g, void* s) {
    __builtin_amdgcn_global_load_lds((const __attribute__((address_space(1))) void*)g,
                                     (__attribute__((address_space(3))) void*)s,
                                     16, 0, 0);
}

// one kernel converts all three fp32 inputs to bf16
__global__ void cvt_all_k(const float* __restrict__ x,  unsigned short* __restrict__ xb,
                          const float* __restrict__ Wp, unsigned short* __restrict__ Wpb,
                          const float* __restrict__ Wv, unsigned short* __restrict__ Wvb)
{
    const int stride = gridDim.x * 256 * 4;
    const int base = (blockIdx.x * 256 + threadIdx.x) * 4;
    for (int i = base; i < M_ * D_; i += stride) {
        float4 v = *(const float4*)(x + i);
        union { unsigned short u[4]; unsigned long long ll; } p;
        p.u[0]=f2bf(v.x); p.u[1]=f2bf(v.y); p.u[2]=f2bf(v.z); p.u[3]=f2bf(v.w);
        *(unsigned long long*)(xb + i) = p.ll;
    }
    for (int i = base; i < P_ * D_; i += stride) {
        float4 v = *(const float4*)(Wp + i);
        union { unsigned short u[4]; unsigned long long ll; } p;
        p.u[0]=f2bf(v.x); p.u[1]=f2bf(v.y); p.u[2]=f2bf(v.z); p.u[3]=f2bf(v.w);
        *(unsigned long long*)(Wpb + i) = p.ll;
    }
    for (int i = base; i < P_ * D_; i += stride) {
        float4 v = *(const float4*)(Wv + i);
        union { unsigned short u[4]; unsigned long long ll; } p;
        p.u[0]=f2bf(v.x); p.u[1]=f2bf(v.y); p.u[2]=f2bf(v.z); p.u[3]=f2bf(v.w);
        *(unsigned long long*)(Wvb + i) = p.ll;
    }
}

// ---------------------------------------------------------------------------
// 256x256-tile, 8-wave, 8-phase counted-vmcnt bf16 GEMM.
// ROUND-2 CHANGE: gray-code quadrant order (0,0)->(1,0)->(1,1)->(0,1) with
// ALL A-fragments held in registers (aR[2][4][2], 64 VGPR — free: occupancy
// is LDS-limited at 1 block/CU). LDS reads per K-tile per wave: 48 -> 24
// b128 (the ideal), removing the LDS-BW bind that capped MfmaUtil at 31%.
//   P1: read A0(8)+B0(4), MFMA (0,0)
//   P2: read A1(8),       MFMA (1,0)
//   P3: read B1(4),       MFMA (1,1)
//   P4: read nothing,     MFMA (0,1)   <- A0,B1 from registers
// Stage-slot schedule and counted vmcnt(4) at P4/P8 unchanged (re-derived:
// every staged region is freed >=1 phase before its overwrite under the new
// read order; buf-ready invariants at P1/P5 identical to the verified r1).
// MODE 0: X1 = f2bf(relu(acc+b)) via LDS-staged coalesced 16B stores.
// MODE 1: out = att[m]*relu(acc+b), direct fp32 stores.
// ---------------------------------------------------------------------------
template<int MODE>
__global__ __launch_bounds__(512, 2) void gemm8p(const unsigned short* __restrict__ A,
                                                 const unsigned short* __restrict__ W,
                                                 const float* __restrict__ bias,
                                                 const float* __restrict__ att,
                                                 void* __restrict__ Cv)
{
    __shared__ unsigned short smem[65536];   // 128 KiB: A0|A1|B0|B1, 16384 shorts each

    // XCD-aware remap: 512 blocks, id&7 = XCD, each XCD gets 16 row-tiles x 4 col-tiles
    const int id  = blockIdx.x;
    const int xcd = id & 7, idx = id >> 3;
    const int bx  = idx & 3;
    const int by  = xcd * 16 + (idx >> 2);
    const int m0  = by << 8, p0 = bx << 8;

    const int t    = threadIdx.x;
    const int lane = t & 63, wave = t >> 6;
    const int wr   = wave >> 2, wc = wave & 3;
    const int lr   = lane & 15, lq = lane >> 4;

    // fragment addressing (identical math to the verified kernel)
    const int aBase = (wr * 64 + lr) * 64;
    const int bBase = (wc * 32 + lr) * 64;
    const int c0 = ((lq       ^ (lr & 7)) & 7) * 8;   // k-half 0 chunk (swizzled)
    const int c1 = (((lq | 4) ^ (lr & 7)) & 7) * 8;   // k-half 1 chunk

    // staging: 1 inst = 64 rows x 128B across 512 threads; per wave dst is
    // wave-uniform base + lane*16B (HW rule); global col pre-swizzled.
    const int srowT = t >> 3;                          // 0..63
    const int slot8 = (t & 7) * 8;
    const int lch8  = (((t & 7) ^ (srowT & 7)) & 7) * 8;
    const unsigned short* Ag = A + ((size_t)m0 << 10) + lch8;
    const unsigned short* Bg = W + ((size_t)p0 << 10) + lch8;

    auto stageA = [&](int buf, int rb, int tt) {       // stages A rows [rb, rb+128)
        const unsigned short* s = Ag + ((size_t)(rb + srowT) << 10) + (tt << 6);
        async_cp16(s,                      smem + buf * 16384 + (rb + srowT) * 64 + slot8);
        async_cp16(s + ((size_t)64 << 10), smem + buf * 16384 + (rb + 64 + srowT) * 64 + slot8);
    };
    auto stageB = [&](int buf, int rb, int tt) {       // stages W rows [rb, rb+128)
        const unsigned short* s = Bg + ((size_t)(rb + srowT) << 10) + (tt << 6);
        async_cp16(s,                      smem + 32768 + buf * 16384 + (rb + srowT) * 64 + slot8);
        async_cp16(s + ((size_t)64 << 10), smem + 32768 + buf * 16384 + (rb + 64 + srowT) * 64 + slot8);
    };

    f32x4 acc[8][4];
    #pragma unroll
    for (int i = 0; i < 8; ++i)
        #pragma unroll
        for (int j = 0; j < 4; ++j) acc[i][j] = (f32x4){0.f, 0.f, 0.f, 0.f};

    // held operand registers: all A fragments + current B quadrant
    bf16x8 aR[2][4][2];   // [mh][i][khalf]
    bf16x8 bR[2][2];      // [j][khalf]

    // prologue: tile0 -> buf0 (8 insts), tile1 -> buf1 (8 insts); wait tile0 only
    stageA(0, 0, 0); stageA(0, 128, 0); stageB(0, 0, 0); stageB(0, 128, 0);
    stageA(1, 0, 1); stageA(1, 128, 1); stageB(1, 0, 1); stageB(1, 128, 1);
    asm volatile("s_waitcnt vmcnt(8)" ::: "memory");
    __builtin_amdgcn_sched_barrier(0);
    __builtin_amdgcn_s_barrier();

#define VMW4 do { asm volatile("s_waitcnt vmcnt(4)" ::: "memory"); \
                  __builtin_amdgcn_sched_barrier(0); } while (0)
#define NOVM ((void)0)
#define PHASE(BUFC, MH, NH, RD_A, RD_B, STAGE_STMT, DO_VM) do {                       \
    if (RD_A) {                                                                       \
        const unsigned short* Ab_ = smem + (BUFC) * 16384 + (MH) * 8192 + aBase;      \
        _Pragma("unroll")                                                             \
        for (int i_ = 0; i_ < 4; ++i_) {                                              \
            aR[MH][i_][0] = *(const bf16x8*)(Ab_ + i_ * 1024 + c0);                   \
            aR[MH][i_][1] = *(const bf16x8*)(Ab_ + i_ * 1024 + c1);                   \
        }                                                                             \
    }                                                                                 \
    if (RD_B) {                                                                       \
        const unsigned short* Bb_ = smem + 32768 + (BUFC) * 16384 + (NH) * 8192 + bBase; \
        _Pragma("unroll")                                                             \
        for (int j_ = 0; j_ < 2; ++j_) {                                              \
            bR[j_][0] = *(const bf16x8*)(Bb_ + j_ * 1024 + c0);                       \
            bR[j_][1] = *(const bf16x8*)(Bb_ + j_ * 1024 + c1);                       \
        }                                                                             \
    }                                                                                 \
    STAGE_STMT;                                                                       \
    __builtin_amdgcn_s_barrier();                                                     \
    asm volatile("s_waitcnt lgkmcnt(0)" ::: "memory");                                \
    __builtin_amdgcn_sched_barrier(0);                                                \
    __builtin_amdgcn_s_setprio(1);                                                    \
    _Pragma("unroll")                                                                 \
    for (int h_ = 0; h_ < 2; ++h_)                                                    \
        _Pragma("unroll")                                                             \
        for (int i_ = 0; i_ < 4; ++i_)                                                \
            _Pragma("unroll")                                                         \
            for (int j_ = 0; j_ < 2; ++j_)                                            \
                acc[(MH) * 4 + i_][(NH) * 2 + j_] =                                   \
                    __builtin_amdgcn_mfma_f32_16x16x32_bf16(                          \
                        aR[MH][i_][h_], bR[j_][h_],                                   \
                        acc[(MH) * 4 + i_][(NH) * 2 + j_], 0, 0, 0);                  \
    __builtin_amdgcn_s_setprio(0);                                                    \
    DO_VM;                                                                            \
    __builtin_amdgcn_s_barrier();                                                     \
} while (0)

    // 8 iterations x 2 K-tiles; staging fills each half-region >=1 phase after
    // its last read under the gray-code order.
    #pragma unroll 1
    for (int it = 0; it < 8; ++it) {
        const int t1 = 2 * it + 1;
        const int t2 = (2 * it + 2) & 15;   // wraps harmlessly on last iter
        const int t3 = (2 * it + 3) & 15;
        PHASE(0, 0, 0, 1, 1, { if (it) stageA(1, 128, t1); }, NOVM);  // buf1.A.mh1 <- t1
        PHASE(0, 1, 0, 1, 0, { if (it) stageB(1, 128, t1); }, NOVM);  // buf1.B.nh1 <- t1
        PHASE(0, 1, 1, 0, 1, stageB(0, 0,   t2), NOVM);               // buf0.B.nh0 <- t2
        PHASE(0, 0, 1, 0, 0, stageA(0, 0,   t2), VMW4);               // buf0.A.mh0 <- t2
        PHASE(1, 0, 0, 1, 1, stageA(0, 128, t2), NOVM);               // buf0.A.mh1 <- t2
        PHASE(1, 1, 0, 1, 0, stageB(0, 128, t2), NOVM);               // buf0.B.nh1 <- t2
        PHASE(1, 1, 1, 0, 1, stageB(1, 0,   t3), NOVM);               // buf1.B.nh0 <- t3
        PHASE(1, 0, 1, 0, 0, stageA(1, 0,   t3), VMW4);               // buf1.A.mh0 <- t3
    }
#undef PHASE
#undef VMW4
#undef NOVM

    // drain stale prefetches before reusing LDS / ending the wave
    asm volatile("s_waitcnt vmcnt(0)" ::: "memory");
    __syncthreads();

    // C/D layout: col = lane&15, row = (lane>>4)*4 + reg   [m89-verified]
    // row = m0 + (mi>>2)*128 + wr*64 + (mi&3)*16 + lq*4 + v
    // col = p0 + (nj>>1)*128 + wc*32 + (nj&1)*16 + lr
    if (MODE == 0) {
        float bi[4];
        #pragma unroll
        for (int nj = 0; nj < 4; ++nj)
            bi[nj] = bias[p0 + ((nj >> 1) << 7) + wc * 32 + ((nj & 1) << 4) + lr];
        unsigned short* Cp = (unsigned short*)Cv;
        #pragma unroll
        for (int mh = 0; mh < 2; ++mh) {          // 128-row half through 64 KiB LDS
            #pragma unroll
            for (int i = 0; i < 4; ++i) {
                const int rl = wr * 64 + i * 16 + lq * 4;
                #pragma unroll
                for (int nj = 0; nj < 4; ++nj) {
                    const int colL = ((nj >> 1) << 7) + wc * 32 + ((nj & 1) << 4) + lr;
                    #pragma unroll
                    for (int v = 0; v < 4; ++v) {
                        const float val = fmaxf(acc[mh * 4 + i][nj][v] + bi[nj], 0.f);
                        smem[(rl + v) * 256 + colL] = f2bf(val);
                    }
                }
            }
            __syncthreads();
            #pragma unroll
            for (int pas = 0; pas < 8; ++pas) {   // coalesced 16B/lane writeback
                const int ix = pas * 512 + t;
                const int row = ix >> 5, ch = ix & 31;
                bf16x8 vv = *(const bf16x8*)(smem + row * 256 + ch * 8);
                *(bf16x8*)(Cp + (size_t)(m0 + mh * 128 + row) * P_ + p0 + ch * 8) = vv;
            }
            __syncthreads();
        }
    } else {
        float* Cp = (float*)Cv;
        #pragma unroll
        for (int mi = 0; mi < 8; ++mi) {
            const int row = m0 + ((mi >> 2) << 7) + wr * 64 + ((mi & 3) << 4) + lq * 4;
            float av[4];
            #pragma unroll
            for (int v = 0; v < 4; ++v) av[v] = att[row + v];
            #pragma unroll
            for (int nj = 0; nj < 4; ++nj) {
                const int col = p0 + ((nj >> 1) << 7) + wc * 32 + ((nj & 1) << 4) + lr;
                const float b0v = bias[col];
                #pragma unroll
                for (int v = 0; v < 4; ++v) {
                    const float val = fmaxf(acc[mi][nj][v] + b0v, 0.f);
                    Cp[(size_t)(row + v) * P_ + col] = val * av[v];
                }
            }
        }
    }
}

// ---------- fallback fp32-staged GEMM (only if ws too small) -----------------
template<int MODE>
__global__ __launch_bounds__(256) void gemm_f32(const float* __restrict__ A,
                                                const float* __restrict__ W,
                                                const float* __restrict__ bias,
                                                const float* __restrict__ att,
                                                void* __restrict__ Cv)
{
    const int K = D_, BK = 32;
    __shared__ float As[128 * 32];
    __shared__ float Bs[128 * 32];
    const int id = blockIdx.x;
    const int bx = (id >> 3) & 7;
    const int by = ((id >> 6) << 3) | (id & 7);
    const int m0 = by * 128, p0 = bx * 128;
    const int wave = threadIdx.x >> 6, lane = threadIdx.x & 63;
    const int wr = wave >> 1, wc = wave & 1;
    const int srow = wave * 32 + (lane >> 3);
    const int scol = (lane & 7) * 4;
    const float* ag = A + (size_t)(m0 + srow) * K + scol;
    const float* bg = W + (size_t)(p0 + srow) * K + scol;
    float* as = &As[srow * BK + scol];
    float* bs = &Bs[srow * BK + scol];
    f32x4 acc[4][4];
    #pragma unroll
    for (int i = 0; i < 4; i++)
        #pragma unroll
        for (int j = 0; j < 4; j++) acc[i][j] = (f32x4){0.f,0.f,0.f,0.f};
    const int lr = lane & 15, lq = lane >> 4;
    const float* Ar = &As[(wr * 64 + lr) * BK + lq * 8];
    const float* Br = &Bs[(wc * 64 + lr) * BK + lq * 8];
    for (int kb = 0; kb < K; kb += BK) {
        #pragma unroll
        for (int s = 0; s < 4; s++) {
            async_cp16(ag + (size_t)s * 8 * K + kb, as + s * 8 * BK);
            async_cp16(bg + (size_t)s * 8 * K + kb, bs + s * 8 * BK);
        }
        __syncthreads();
        bf16x8 af[4], bf[4];
        #pragma unroll
        for (int i = 0; i < 4; i++) {
            f32x4 a0 = *(const f32x4*)(Ar + i * 16 * BK);
            f32x4 a1 = *(const f32x4*)(Ar + i * 16 * BK + 4);
            #pragma unroll
            for (int e = 0; e < 4; e++) {
                union { float f; unsigned int u; } c;
                c.f = a0[e]; af[i][e]     = (short)(c.u >> 16);
                c.f = a1[e]; af[i][e + 4] = (short)(c.u >> 16);
            }
        }
        #pragma unroll
        for (int j = 0; j < 4; j++) {
            f32x4 b0 = *(const f32x4*)(Br + j * 16 * BK);
            f32x4 b1 = *(const f32x4*)(Br + j * 16 * BK + 4);
            #pragma unroll
            for (int e = 0; e < 4; e++) {
                union { float f; unsigned int u; } c;
                c.f = b0[e]; bf[j][e]     = (short)(c.u >> 16);
                c.f = b1[e]; bf[j][e + 4] = (short)(c.u >> 16);
            }
        }
        #pragma unroll
        for (int i = 0; i < 4; i++)
            #pragma unroll
            for (int j = 0; j < 4; j++)
                acc[i][j] = __builtin_amdgcn_mfma_f32_16x16x32_bf16(af[i], bf[j], acc[i][j], 0, 0, 0);
        __syncthreads();
    }
    const int crow0 = m0 + wr * 64 + lq * 4;
    const int ccol0 = p0 + wc * 64 + lr;
    #pragma unroll
    for (int i = 0; i < 4; i++) {
        float attv[4];
        if (MODE == 1) {
            #pragma unroll
            for (int v = 0; v < 4; v++) attv[v] = att[crow0 + i * 16 + v];
        }
        #pragma unroll
        for (int j = 0; j < 4; j++) {
            const int col = ccol0 + j * 16;
            const float bi = bias[col];
            #pragma unroll
            for (int v = 0; v < 4; v++) {
                const int row = crow0 + i * 16 + v;
                float val = fmaxf(acc[i][j][v] + bi, 0.0f);
                if (MODE == 0) ((unsigned short*)Cv)[(size_t)row * P_ + col] = f2bf(val);
                else           ((float*)Cv)[(size_t)row * P_ + col] = val * attv[v];
            }
        }
    }
}

// ---------- fused rownorm + weighted column-reduce + mask-sum ----------------
// grid (64 nchunks, 16 b) = 1024 blocks (4/CU); wave handles 8 rows.
__global__ __launch_bounds__(256) void fused_nc_k(const unsigned short* __restrict__ X1,
                                                  const float* __restrict__ mask,
                                                  float* __restrict__ inv,
                                                  float* __restrict__ wsv,
                                                  float* __restrict__ msum)
{
    __shared__ float accw[4][1024];
    __shared__ float mred[4];
    const int b = blockIdx.y, nc = blockIdx.x;
    const int wave = threadIdx.x >> 6, lane = threadIdx.x & 63;
    float acc[16];
    #pragma unroll
    for (int e = 0; e < 16; e++) acc[e] = 0.f;
    float msub = 0.f;
    const int rbase = b * N_ + nc * 32 + wave * 8;
    const int nbase = nc * 32 + wave * 8;
    for (int t = 0; t < 8; t++) {
        const int r = rbase + t;
        const unsigned short* row = X1 + (size_t)r * P_;
        bf16x8 u0 = *(const bf16x8*)(row + lane * 16);
        bf16x8 u1 = *(const bf16x8*)(row + lane * 16 + 8);
        float v[16], s = 0.f;
        #pragma unroll
        for (int e = 0; e < 8; e++) { v[e] = bf2f((unsigned short)u0[e]); s += v[e]*v[e]; }
        #pragma unroll
        for (int e = 0; e < 8; e++) { v[8+e] = bf2f((unsigned short)u1[e]); s += v[8+e]*v[8+e]; }
        #pragma unroll
        for (int off = 32; off > 0; off >>= 1) s += __shfl_down(s, off);
        s = __shfl(s, 0);
        const float iv = 1.f / (sqrtf(s) + 1e-8f);
        const float mk = mask[(nbase + t) * B_ + b];
        if (lane == 0) { inv[r] = iv; msub += mk; }
        const float w = mk * iv;
        #pragma unroll
        for (int e = 0; e < 16; e++) acc[e] += w * v[e];
    }
    #pragma unroll
    for (int e = 0; e < 16; e++) accw[wave][e * 64 + lane] = acc[e];   // transposed
    if (lane == 0) mred[wave] = msub;
    __syncthreads();
    #pragma unroll
    for (int q = 0; q < 4; q++) {
        const int p = threadIdx.x * 4 + q;
        const int col = (p & 63) * 16 + (p >> 6);
        float ssum = accw[0][p] + accw[1][p] + accw[2][p] + accw[3][p];
        atomicAdd(&wsv[b * P_ + col], ssum);
    }
    if (threadIdx.x == 0) atomicAdd(&msum[b], mred[0] + mred[1] + mred[2] + mred[3]);
}

// att[r] = inv[r] * <X1[r,:], wsv[b,:]> / msum[b]; one wave per row
__global__ void att_k(const unsigned short* __restrict__ X1,
                      const float* __restrict__ wsvec,
                      const float* __restrict__ inv,
                      const float* __restrict__ msum,
                      float* __restrict__ att)
{
    const int r = blockIdx.x * 4 + (threadIdx.x >> 6);
    const int lane = threadIdx.x & 63;
    const int b = r >> 11;
    const unsigned short* row = X1 + (size_t)r * P_;
    const float* w = wsvec + b * P_;
    bf16x8 u0 = *(const bf16x8*)(row + lane * 8);
    bf16x8 u1 = *(const bf16x8*)(row + 512 + lane * 8);
    f32x4 w0 = *(const f32x4*)(w + lane * 8);
    f32x4 w1 = *(const f32x4*)(w + lane * 8 + 4);
    f32x4 w2 = *(const f32x4*)(w + 512 + lane * 8);
    f32x4 w3 = *(const f32x4*)(w + 512 + lane * 8 + 4);
    float s = 0.f;
    #pragma unroll
    for (int k = 0; k < 4; k++) s += bf2f((unsigned short)u0[k]) * w0[k];
    #pragma unroll
    for (int k = 0; k < 4; k++) s += bf2f((unsigned short)u0[k + 4]) * w1[k];
    #pragma unroll
    for (int k = 0; k < 4; k++) s += bf2f((unsigned short)u1[k]) * w2[k];
    #pragma unroll
    for (int k = 0; k < 4; k++) s += bf2f((unsigned short)u1[k + 4]) * w3[k];
    #pragma unroll
    for (int off = 32; off > 0; off >>= 1) s += __shfl_down(s, off);
    if (lane == 0) att[r] = s * inv[r] / msum[b];
}

extern "C" void kernel_launch(void* const* d_in, const int* in_sizes, int n_in,
                              void* d_out, int out_size, void* d_ws, size_t ws_size,
                              hipStream_t stream)
{
    const float* x    = (const float*)d_in[0];
    const float* mask = (const float*)d_in[1];
    const float* Wp   = (const float*)d_in[2];
    const float* bp   = (const float*)d_in[3];
    const float* Wv   = (const float*)d_in[4];
    const float* bv   = (const float*)d_in[5];
    float* out = (float*)d_out;

    // X1 (bf16, 64 MiB) parks in d_out's first half; dead before GEMM2 stores.
    unsigned short* X1 = (unsigned short*)d_out;

    const size_t xb_bytes = (size_t)M_ * D_ * 2;
    const size_t wb_bytes = (size_t)P_ * D_ * 2;
    const size_t f_bytes  = 2 * (size_t)M_ * 4 + (size_t)B_ * P_ * 4 + 64;
    const bool big_ws = ws_size >= xb_bytes + 2 * wb_bytes + f_bytes;

    char* ws = (char*)d_ws;
    size_t off = 0;
    unsigned short *xb = nullptr, *Wpb = nullptr, *Wvb = nullptr;
    if (big_ws) {
        xb  = (unsigned short*)(ws + off); off += xb_bytes;
        Wpb = (unsigned short*)(ws + off); off += wb_bytes;
        Wvb = (unsigned short*)(ws + off); off += wb_bytes;
    }
    float* inv  = (float*)(ws + off); off += (size_t)M_ * 4;
    float* att  = (float*)(ws + off); off += (size_t)M_ * 4;
    float* wsv  = (float*)(ws + off); off += (size_t)B_ * P_ * 4;
    float* msum = (float*)(ws + off); off += 64;

    hipMemsetAsync(wsv, 0, (size_t)B_ * P_ * 4 + 64, stream);

    if (big_ws) {
        cvt_all_k<<<2048, 256, 0, stream>>>(x, xb, Wp, Wpb, Wv, Wvb);
        gemm8p<0><<<512, 512, 0, stream>>>(xb, Wpb, bp, nullptr, X1);
    } else {
        const int gblocks = (P_ / 128) * (M_ / 128);
        gemm_f32<0><<<gblocks, 256, 0, stream>>>(x, Wp, bp, nullptr, X1);
    }
    fused_nc_k<<<dim3(64, B_), 256, 0, stream>>>(X1, mask, inv, wsv, msum);
    att_k<<<M_ / 4, 256, 0, stream>>>(X1, wsv, inv, msum, att);
    if (big_ws) gemm8p<1><<<512, 512, 0, stream>>>(xb, Wvb, bv, att, out);
    else {
        const int gblocks = (P_ / 128) * (M_ / 128);
        gemm_f32<1><<<gblocks, 256, 0, stream>>>(x, Wv, bv, att, out);
    }
}